// Round 4
// baseline (412.895 us; speedup 1.0000x reference)
//
#include <hip/hip_runtime.h>

#define D_MODEL 1024
#define N_HEADS 16
#define D_K     64
#define BATCH   4
#define SEQ     2048
#define MROWS   (BATCH * SEQ)          // 8192

typedef __bf16 bf16x8 __attribute__((ext_vector_type(8)));
typedef float  f32x4  __attribute__((ext_vector_type(4)));
typedef unsigned short ushort8 __attribute__((ext_vector_type(8)));
typedef unsigned short ushort4v __attribute__((ext_vector_type(4)));

__device__ inline unsigned short f2bf(float f) {
    union { float f; unsigned int u; } v; v.f = f;
    unsigned int u = v.u;
    unsigned int r = (u + 0x7fffu + ((u >> 16) & 1u)) >> 16;
    return (unsigned short)r;
}

__device__ inline void load_lds16(const void* g, void* l) {
    __builtin_amdgcn_global_load_lds(
        (const __attribute__((address_space(1))) unsigned int*)g,
        (__attribute__((address_space(3))) unsigned int*)l, 16, 0, 0);
}

// ---------------- prep: weights fp32 [K][N] -> bf16 [N][K] ----------------
__global__ __launch_bounds__(256) void wprep(const float* __restrict__ Wq,
                                             const float* __restrict__ Wk,
                                             const float* __restrict__ Wv,
                                             const float* __restrict__ Wo,
                                             unsigned short* __restrict__ wt) {
    __shared__ __align__(16) unsigned short t[64][65];
    int w  = blockIdx.z;
    const float* W = (w == 0) ? Wq : (w == 1) ? Wk : (w == 2) ? Wv : Wo;
    int k0 = blockIdx.x * 64, n0 = blockIdx.y * 64;
    int tid = threadIdx.x;
    int nl = tid & 63, kq = tid >> 6;
#pragma unroll
    for (int i = 0; i < 16; i++) {
        int kl = kq * 16 + i;
        t[kl][nl] = f2bf(W[(size_t)(k0 + kl) * D_MODEL + n0 + nl]);
    }
    __syncthreads();
    unsigned short* out = wt + (size_t)w * D_MODEL * D_MODEL;
#pragma unroll
    for (int p = 0; p < 2; p++) {
        int nrow = p * 32 + (tid >> 3);
        int c8   = (tid & 7) * 8;
        ushort8 o;
#pragma unroll
        for (int j = 0; j < 8; j++) o[j] = t[c8 + j][nrow];
        *reinterpret_cast<ushort8*>(out + (size_t)(n0 + nrow) * D_MODEL + k0 + c8) = o;
    }
}

// ---------------- prep: x fp32 -> bf16 ----------------
__global__ __launch_bounds__(256) void xprep(const float4* __restrict__ x,
                                             unsigned short* __restrict__ xb) {
    int i = blockIdx.x * 256 + threadIdx.x;   // over MROWS*D_MODEL/4
    float4 v = x[i];
    ushort4v o;
    o[0] = f2bf(v.x); o[1] = f2bf(v.y); o[2] = f2bf(v.z); o[3] = f2bf(v.w);
    *reinterpret_cast<ushort4v*>(xb + (size_t)i * 4) = o;
}

// ---------------- prep: mask int32 -> bitmask (bit=1 means masked) --------
__global__ __launch_bounds__(256) void mprep(const int* __restrict__ mask,
                                             unsigned long long* __restrict__ mb) {
    int row = blockIdx.x;                 // b*SEQ + q
    int tid = threadIdx.x;
    int wv  = tid >> 6;
#pragma unroll
    for (int w = 0; w < 8; w++) {
        int col = w * 256 + tid;
        int mval = mask[(size_t)row * SEQ + col];
        unsigned long long bits = __ballot(mval != 0);
        if ((tid & 63) == 0) mb[(size_t)row * 32 + w * 4 + wv] = bits;
    }
}

// ============ fused QKV GEMM: m97 structure, M=8192 N=3072 K=1024 =========
__global__ __launch_bounds__(256) void qkv_gemm(const unsigned short* __restrict__ xb,
                                                const unsigned short* __restrict__ wt,
                                                const float* __restrict__ bq,
                                                const float* __restrict__ bk,
                                                const float* __restrict__ bvv,
                                                unsigned short* __restrict__ qb,
                                                unsigned short* __restrict__ kb,
                                                unsigned short* __restrict__ vt) {
    __shared__ __align__(16) unsigned short lds_a[128 * 32];
    __shared__ __align__(16) unsigned short lds_b[128 * 32];
    int tid = threadIdx.x;
    int wave = tid >> 6, lane = tid & 63;
    int c = lane & 15, g = lane >> 4;
    int wave_m = (wave & 1) * 64, wave_n = (wave >> 1) * 64;
    int nblk = blockIdx.x * 128, mblk = blockIdx.y * 128;

    int oct0 = wave * 128 + lane, oct1 = oct0 + 64;
    int ra0 = oct0 >> 2, ga0 = ((oct0 & 3) ^ (ra0 & 3)) * 8;
    int ra1 = oct1 >> 2, ga1 = ((oct1 & 3) ^ (ra1 & 3)) * 8;
    const unsigned short* pa0 = xb + (size_t)(mblk + ra0) * D_MODEL + ga0;
    const unsigned short* pa1 = xb + (size_t)(mblk + ra1) * D_MODEL + ga1;
    const unsigned short* pb0 = wt + (size_t)(nblk + ra0) * D_MODEL + ga0;
    const unsigned short* pb1 = wt + (size_t)(nblk + ra1) * D_MODEL + ga1;
    unsigned short* la0 = lds_a + wave * 1024;
    unsigned short* la1 = la0 + 512;
    unsigned short* lb0 = lds_b + wave * 1024;
    unsigned short* lb1 = lb0 + 512;

    int aoff[4], boff[4];
#pragma unroll
    for (int mi = 0; mi < 4; mi++) {
        int row = wave_m + mi * 16 + c;
        aoff[mi] = (row * 4 + (g ^ (row & 3))) * 16;
    }
#pragma unroll
    for (int ni = 0; ni < 4; ni++) {
        int row = wave_n + ni * 16 + c;
        boff[ni] = (row * 4 + (g ^ (row & 3))) * 16;
    }

    f32x4 acc[4][4];
#pragma unroll
    for (int mi = 0; mi < 4; mi++)
#pragma unroll
        for (int ni = 0; ni < 4; ni++) acc[mi][ni] = f32x4{0.f, 0.f, 0.f, 0.f};

    for (int k0 = 0; k0 < D_MODEL; k0 += 32) {
        load_lds16(pa0 + k0, la0);
        load_lds16(pa1 + k0, la1);
        load_lds16(pb0 + k0, lb0);
        load_lds16(pb1 + k0, lb1);
        __syncthreads();
        bf16x8 af[4], bfr[4];
#pragma unroll
        for (int mi = 0; mi < 4; mi++)
            af[mi] = *reinterpret_cast<const bf16x8*>(reinterpret_cast<const char*>(lds_a) + aoff[mi]);
#pragma unroll
        for (int ni = 0; ni < 4; ni++)
            bfr[ni] = *reinterpret_cast<const bf16x8*>(reinterpret_cast<const char*>(lds_b) + boff[ni]);
#pragma unroll
        for (int mi = 0; mi < 4; mi++)
#pragma unroll
            for (int ni = 0; ni < 4; ni++)
                acc[mi][ni] = __builtin_amdgcn_mfma_f32_16x16x32_bf16(af[mi], bfr[ni], acc[mi][ni], 0, 0, 0);
        __syncthreads();
    }

    int nb = nblk + wave_n;
    int wsel = nb >> 10;
    int h = (nb >> 6) & 15;
    int dk0 = nb & 63;
    int mglob = mblk + wave_m;
    int b = mglob >> 11;
    int s0 = mglob & (SEQ - 1);
    size_t bh = (size_t)(b * N_HEADS + h);
    const float* bias = (wsel == 0) ? bq : (wsel == 1) ? bk : bvv;
    int nn = nb & (D_MODEL - 1);
    float bval[4];
#pragma unroll
    for (int ni = 0; ni < 4; ni++) bval[ni] = bias[nn + ni * 16 + c];

    if (wsel < 2) {
        unsigned short* outp = wsel ? kb : qb;
#pragma unroll
        for (int mi = 0; mi < 4; mi++)
#pragma unroll
            for (int ni = 0; ni < 4; ni++) {
                int dk = dk0 + ni * 16 + c;
#pragma unroll
                for (int r = 0; r < 4; r++) {
                    int s = s0 + mi * 16 + g * 4 + r;
                    outp[(bh * SEQ + s) * 64 + dk] = f2bf(acc[mi][ni][r] + bval[ni]);
                }
            }
    } else {
#pragma unroll
        for (int mi = 0; mi < 4; mi++)
#pragma unroll
            for (int ni = 0; ni < 4; ni++) {
                int dk = dk0 + ni * 16 + c;
                int s = s0 + mi * 16 + g * 4;
                ushort4v o;
#pragma unroll
                for (int r = 0; r < 4; r++) o[r] = f2bf(acc[mi][ni][r] + bval[ni]);
                *reinterpret_cast<ushort4v*>(vt + (bh * 64 + dk) * SEQ + s) = o;
            }
    }
}

// ==== flash attention v3: double-buffered K/V, S^T layout, lean softmax ====
// block = 4 waves = 64 queries of one head; key tile = 64, one barrier/step
__global__ __launch_bounds__(256) void attn(const unsigned short* __restrict__ qb,
                                            const unsigned short* __restrict__ kb,
                                            const unsigned short* __restrict__ vt,
                                            const unsigned long long* __restrict__ mb,
                                            unsigned short* __restrict__ ctx) {
    __shared__ __align__(16) unsigned short lds_k[2][64 * 64];   // [buf][key][dk] swizzled
    __shared__ __align__(16) unsigned short lds_v[2][64 * 64];   // [buf][dk][key] swizzled
    __shared__ __align__(16) unsigned short lp[4][16][72];       // per-wave P [query][key]
    int tid = threadIdx.x;
    int wave = tid >> 6, lane = tid & 63;
    int c = lane & 15, g = lane >> 4;
    int bh = blockIdx.x >> 5;
    int q0 = (blockIdx.x & 31) * 64 + wave * 16;
    int b = bh >> 4;
    const unsigned short* qbase = qb + (size_t)bh * SEQ * 64;
    const unsigned short* kbase = kb + (size_t)bh * SEQ * 64;
    const unsigned short* vbase = vt + (size_t)bh * 64 * SEQ;
    // per-lane mask row: query q0+c (one u64 per 64-key step)
    const unsigned long long* mrowp = mb + ((size_t)b * SEQ + q0 + c) * 32;

    // Q fragment (B-operand): lane holds Q[q0+c][dk = g*8 + j]
    bf16x8 qf0 = *reinterpret_cast<const bf16x8*>(qbase + (size_t)(q0 + c) * 64 + g * 8);
    bf16x8 qf1 = *reinterpret_cast<const bf16x8*>(qbase + (size_t)(q0 + c) * 64 + 32 + g * 8);

    // staging: slot j covers 8 ushorts; row = j>>3 (64 rows), octet swizzle o^(row&7)
    int j0 = wave * 128 + lane, j1 = j0 + 64;
    int sr0 = j0 >> 3, so0 = (j0 & 7) ^ (sr0 & 7);
    int sr1 = j1 >> 3, so1 = (j1 & 7) ^ (sr1 & 7);
    const unsigned short* ks0 = kbase + (size_t)sr0 * 64 + so0 * 8;
    const unsigned short* ks1 = kbase + (size_t)sr1 * 64 + so1 * 8;
    const unsigned short* vs0 = vbase + (size_t)sr0 * SEQ + so0 * 8;
    const unsigned short* vs1 = vbase + (size_t)sr1 * SEQ + so1 * 8;

    // fragment byte offsets within one buffer (constant over key loop)
    int koff[4][2], voff[4][2];
#pragma unroll
    for (int st = 0; st < 4; st++) {
        int row = st * 16 + c;
#pragma unroll
        for (int kk = 0; kk < 2; kk++)
            koff[st][kk] = (row * 8 + ((kk * 4 + g) ^ (row & 7))) * 16;
    }
#pragma unroll
    for (int t = 0; t < 4; t++) {
        int row = t * 16 + c;
#pragma unroll
        for (int kk = 0; kk < 2; kk++)
            voff[t][kk] = (row * 8 + ((kk * 4 + g) ^ (row & 7))) * 16;
    }

    // prefetch tile 0 + mask word 0
    load_lds16(ks0, &lds_k[0][wave * 1024]);
    load_lds16(ks1, &lds_k[0][wave * 1024 + 512]);
    load_lds16(vs0, &lds_v[0][wave * 1024]);
    load_lds16(vs1, &lds_v[0][wave * 1024 + 512]);
    unsigned long long wcur = mrowp[0];

    float lsum = 0.f;
    f32x4 po[4];
#pragma unroll
    for (int t = 0; t < 4; t++) po[t] = f32x4{0.f, 0.f, 0.f, 0.f};

    for (int it = 0; it < SEQ / 64; it++) {
        int cur = it & 1;
        __syncthreads();                         // tile `cur` ready (vmcnt drained)
        if (it + 1 < SEQ / 64) {                 // prefetch tile it+1 into other buffer
            int nxt = cur ^ 1;
            int key0n = (it + 1) * 64;
            load_lds16(ks0 + (size_t)key0n * 64, &lds_k[nxt][wave * 1024]);
            load_lds16(ks1 + (size_t)key0n * 64, &lds_k[nxt][wave * 1024 + 512]);
            load_lds16(vs0 + key0n, &lds_v[nxt][wave * 1024]);
            load_lds16(vs1 + key0n, &lds_v[nxt][wave * 1024 + 512]);
        }
        unsigned long long wnx = (it + 1 < SEQ / 64) ? mrowp[it + 1] : 0ull;
        const char* lk = reinterpret_cast<const char*>(&lds_k[cur][0]);
        const char* lv = reinterpret_cast<const char*>(&lds_v[cur][0]);

        // S^T: A = K (m = key), B = Q (n = query) -> s[st][r]: key = st*16+g*4+r, query = c
        f32x4 s[4];
#pragma unroll
        for (int st = 0; st < 4; st++) {
            s[st] = f32x4{0.f, 0.f, 0.f, 0.f};
            s[st] = __builtin_amdgcn_mfma_f32_16x16x32_bf16(
                *reinterpret_cast<const bf16x8*>(lk + koff[st][0]), qf0, s[st], 0, 0, 0);
            s[st] = __builtin_amdgcn_mfma_f32_16x16x32_bf16(
                *reinterpret_cast<const bf16x8*>(lk + koff[st][1]), qf1, s[st], 0, 0, 0);
        }

        // softmax numerators: p = exp(s/8), zero+truncate via sign-mask AND
        unsigned int a0 = ~(unsigned int)wcur;           // bit=1 -> keep
        unsigned int a1 = ~(unsigned int)(wcur >> 32);
        wcur = wnx;
#pragma unroll
        for (int st = 0; st < 4; st++) {
            unsigned int aw = (st < 2) ? a0 : a1;
            int base = 31 - ((st & 1) << 4) - g * 4;     // shl amount for r=0
            unsigned int pt[4];
#pragma unroll
            for (int r = 0; r < 4; r++) {
                unsigned int m2 = (unsigned int)((int)(aw << (base - r)) >> 31) & 0xFFFF0000u;
                float p = __expf(s[st][r] * 0.125f);
                unsigned int tt = __float_as_uint(p) & m2;   // masked->0, else bf16-truncated
                lsum += __uint_as_float(tt);
                pt[r] = tt;
            }
            uint2 u;
            u.x = (pt[0] >> 16) | pt[1];
            u.y = (pt[2] >> 16) | pt[3];
            *reinterpret_cast<uint2*>(&lp[wave][c][st * 16 + g * 4]) = u;
        }

        // PV: A = P (m = query, k = key), B = V (n = dk)
        bf16x8 pf0 = *reinterpret_cast<const bf16x8*>(&lp[wave][c][g * 8]);
        bf16x8 pf1 = *reinterpret_cast<const bf16x8*>(&lp[wave][c][32 + g * 8]);
#pragma unroll
        for (int t = 0; t < 4; t++) {
            po[t] = __builtin_amdgcn_mfma_f32_16x16x32_bf16(
                pf0, *reinterpret_cast<const bf16x8*>(lv + voff[t][0]), po[t], 0, 0, 0);
            po[t] = __builtin_amdgcn_mfma_f32_16x16x32_bf16(
                pf1, *reinterpret_cast<const bf16x8*>(lv + voff[t][1]), po[t], 0, 0, 0);
        }
    }

    // lane holds lsum for query c (partial over g); finish across g-groups
    lsum += __shfl_xor(lsum, 16);
    lsum += __shfl_xor(lsum, 32);
    float invr[4];
#pragma unroll
    for (int r = 0; r < 4; r++)
        invr[r] = 1.f / __shfl(lsum, g * 4 + r);   // total for query row g*4+r sits on lane g*4+r

    int h = bh & 15;
#pragma unroll
    for (int t = 0; t < 4; t++)
#pragma unroll
        for (int r = 0; r < 4; r++) {
            int row = g * 4 + r;
            ctx[((size_t)b * SEQ + q0 + row) * D_MODEL + h * 64 + t * 16 + c] = f2bf(po[t][r] * invr[r]);
        }
}

// ============ output projection: m97 structure, M=8192 N=1024 K=1024 ======
__global__ __launch_bounds__(256) void oproj(const unsigned short* __restrict__ ctx,
                                             const unsigned short* __restrict__ wt,
                                             const float* __restrict__ bo,
                                             float* __restrict__ out) {
    __shared__ __align__(16) unsigned short lds_a[128 * 32];
    __shared__ __align__(16) unsigned short lds_b[128 * 32];
    int tid = threadIdx.x;
    int wave = tid >> 6, lane = tid & 63;
    int c = lane & 15, g = lane >> 4;
    int wave_m = (wave & 1) * 64, wave_n = (wave >> 1) * 64;
    int nblk = blockIdx.x * 128, mblk = blockIdx.y * 128;
    const unsigned short* wo = wt + (size_t)3 * D_MODEL * D_MODEL;

    int oct0 = wave * 128 + lane, oct1 = oct0 + 64;
    int ra0 = oct0 >> 2, ga0 = ((oct0 & 3) ^ (ra0 & 3)) * 8;
    int ra1 = oct1 >> 2, ga1 = ((oct1 & 3) ^ (ra1 & 3)) * 8;
    const unsigned short* pa0 = ctx + (size_t)(mblk + ra0) * D_MODEL + ga0;
    const unsigned short* pa1 = ctx + (size_t)(mblk + ra1) * D_MODEL + ga1;
    const unsigned short* pb0 = wo + (size_t)(nblk + ra0) * D_MODEL + ga0;
    const unsigned short* pb1 = wo + (size_t)(nblk + ra1) * D_MODEL + ga1;
    unsigned short* la0 = lds_a + wave * 1024;
    unsigned short* la1 = la0 + 512;
    unsigned short* lb0 = lds_b + wave * 1024;
    unsigned short* lb1 = lb0 + 512;

    int aoff[4], boff[4];
#pragma unroll
    for (int mi = 0; mi < 4; mi++) {
        int row = wave_m + mi * 16 + c;
        aoff[mi] = (row * 4 + (g ^ (row & 3))) * 16;
    }
#pragma unroll
    for (int ni = 0; ni < 4; ni++) {
        int row = wave_n + ni * 16 + c;
        boff[ni] = (row * 4 + (g ^ (row & 3))) * 16;
    }

    f32x4 acc[4][4];
#pragma unroll
    for (int mi = 0; mi < 4; mi++)
#pragma unroll
        for (int ni = 0; ni < 4; ni++) acc[mi][ni] = f32x4{0.f, 0.f, 0.f, 0.f};

    for (int k0 = 0; k0 < D_MODEL; k0 += 32) {
        load_lds16(pa0 + k0, la0);
        load_lds16(pa1 + k0, la1);
        load_lds16(pb0 + k0, lb0);
        load_lds16(pb1 + k0, lb1);
        __syncthreads();
        bf16x8 af[4], bfr[4];
#pragma unroll
        for (int mi = 0; mi < 4; mi++)
            af[mi] = *reinterpret_cast<const bf16x8*>(reinterpret_cast<const char*>(lds_a) + aoff[mi]);
#pragma unroll
        for (int ni = 0; ni < 4; ni++)
            bfr[ni] = *reinterpret_cast<const bf16x8*>(reinterpret_cast<const char*>(lds_b) + boff[ni]);
#pragma unroll
        for (int mi = 0; mi < 4; mi++)
#pragma unroll
            for (int ni = 0; ni < 4; ni++)
                acc[mi][ni] = __builtin_amdgcn_mfma_f32_16x16x32_bf16(af[mi], bfr[ni], acc[mi][ni], 0, 0, 0);
        __syncthreads();
    }

    float bval[4];
#pragma unroll
    for (int ni = 0; ni < 4; ni++) bval[ni] = bo[nblk + wave_n + ni * 16 + c];
#pragma unroll
    for (int mi = 0; mi < 4; mi++)
#pragma unroll
        for (int ni = 0; ni < 4; ni++) {
            int n = nblk + wave_n + ni * 16 + c;
#pragma unroll
            for (int r = 0; r < 4; r++) {
                int m = mblk + wave_m + mi * 16 + g * 4 + r;
                out[(size_t)m * D_MODEL + n] = acc[mi][ni][r] + bval[ni];
            }
        }
}

extern "C" void kernel_launch(void* const* d_in, const int* in_sizes, int n_in,
                              void* d_out, int out_size, void* d_ws, size_t ws_size,
                              hipStream_t stream) {
    const float* x    = (const float*)d_in[0];
    const int*   mask = (const int*)d_in[1];
    const float* Wq = (const float*)d_in[2];
    const float* bq = (const float*)d_in[3];
    const float* Wk = (const float*)d_in[4];
    const float* bk = (const float*)d_in[5];
    const float* Wv = (const float*)d_in[6];
    const float* bv = (const float*)d_in[7];
    const float* Wo = (const float*)d_in[8];
    const float* bo = (const float*)d_in[9];
    float* out = (float*)d_out;

    char* ws = (char*)d_ws;
    const size_t MB = 1024 * 1024;
    unsigned short* wt  = (unsigned short*)(ws + 0 * MB);    // 4x 1024x1024 bf16 = 8 MB
    unsigned short* xb  = (unsigned short*)(ws + 8 * MB);    // 8192x1024 bf16   = 16 MB
    unsigned short* qb  = (unsigned short*)(ws + 24 * MB);   // [B,H,S,dk] bf16  = 16 MB
    unsigned short* kb  = (unsigned short*)(ws + 40 * MB);   // [B,H,S,dk] bf16  = 16 MB
    unsigned short* vt  = (unsigned short*)(ws + 56 * MB);   // [B,H,dk,S] bf16  = 16 MB
    unsigned short* ctx = (unsigned short*)(ws + 72 * MB);   // [B,S,D] bf16     = 16 MB
    unsigned long long* mb = (unsigned long long*)(ws + 88 * MB); // 8192x32 u64 = 2 MB

    wprep<<<dim3(16, 16, 4), 256, 0, stream>>>(Wq, Wk, Wv, Wo, wt);
    xprep<<<dim3(MROWS * D_MODEL / 4 / 256), 256, 0, stream>>>((const float4*)x, xb);
    mprep<<<dim3(MROWS), 256, 0, stream>>>(mask, mb);
    qkv_gemm<<<dim3(24, 64), 256, 0, stream>>>(xb, wt, bq, bk, bv, qb, kb, vt);
    attn<<<dim3(2048), 256, 0, stream>>>(qb, kb, vt, mb, ctx);
    oproj<<<dim3(8, 64), 256, 0, stream>>>(ctx, wt, bo, out);
}

// Round 5
// 411.488 us; speedup vs baseline: 1.0034x; 1.0034x over previous
//
#include <hip/hip_runtime.h>

#define D_MODEL 1024
#define N_HEADS 16
#define D_K     64
#define BATCH   4
#define SEQ     2048
#define MROWS   (BATCH * SEQ)          // 8192
// Q pre-scale: (1/sqrt(64)) * log2(e) so attn uses raw exp2
#define QSCALE  0.18033688011112042f

typedef __bf16 bf16x8 __attribute__((ext_vector_type(8)));
typedef float  f32x4  __attribute__((ext_vector_type(4)));
typedef float  f32x16 __attribute__((ext_vector_type(16)));
typedef unsigned short ushort8 __attribute__((ext_vector_type(8)));
typedef unsigned short ushort4v __attribute__((ext_vector_type(4)));

#if __has_builtin(__builtin_amdgcn_exp2f)
#define EXP2F(x) __builtin_amdgcn_exp2f(x)
#else
#define EXP2F(x) exp2f(x)
#endif

__device__ inline unsigned short f2bf(float f) {
    union { float f; unsigned int u; } v; v.f = f;
    unsigned int u = v.u;
    unsigned int r = (u + 0x7fffu + ((u >> 16) & 1u)) >> 16;
    return (unsigned short)r;
}

__device__ inline void load_lds16(const void* g, void* l) {
    __builtin_amdgcn_global_load_lds(
        (const __attribute__((address_space(1))) unsigned int*)g,
        (__attribute__((address_space(3))) unsigned int*)l, 16, 0, 0);
}

// ---------------- prep: weights fp32 [K][N] -> bf16 [N][K] ----------------
__global__ __launch_bounds__(256) void wprep(const float* __restrict__ Wq,
                                             const float* __restrict__ Wk,
                                             const float* __restrict__ Wv,
                                             const float* __restrict__ Wo,
                                             unsigned short* __restrict__ wt) {
    __shared__ __align__(16) unsigned short t[64][65];
    int w  = blockIdx.z;
    const float* W = (w == 0) ? Wq : (w == 1) ? Wk : (w == 2) ? Wv : Wo;
    int k0 = blockIdx.x * 64, n0 = blockIdx.y * 64;
    int tid = threadIdx.x;
    int nl = tid & 63, kq = tid >> 6;
#pragma unroll
    for (int i = 0; i < 16; i++) {
        int kl = kq * 16 + i;
        t[kl][nl] = f2bf(W[(size_t)(k0 + kl) * D_MODEL + n0 + nl]);
    }
    __syncthreads();
    unsigned short* out = wt + (size_t)w * D_MODEL * D_MODEL;
#pragma unroll
    for (int p = 0; p < 2; p++) {
        int nrow = p * 32 + (tid >> 3);
        int c8   = (tid & 7) * 8;
        ushort8 o;
#pragma unroll
        for (int j = 0; j < 8; j++) o[j] = t[c8 + j][nrow];
        *reinterpret_cast<ushort8*>(out + (size_t)(n0 + nrow) * D_MODEL + k0 + c8) = o;
    }
}

// ---------------- prep: x fp32 -> bf16 ----------------
__global__ __launch_bounds__(256) void xprep(const float4* __restrict__ x,
                                             unsigned short* __restrict__ xb) {
    int i = blockIdx.x * 256 + threadIdx.x;
    float4 v = x[i];
    ushort4v o;
    o[0] = f2bf(v.x); o[1] = f2bf(v.y); o[2] = f2bf(v.z); o[3] = f2bf(v.w);
    *reinterpret_cast<ushort4v*>(xb + (size_t)i * 4) = o;
}

// ---------------- prep: mask int32 -> bitmask (bit=1 means masked) --------
__global__ __launch_bounds__(256) void mprep(const int* __restrict__ mask,
                                             unsigned long long* __restrict__ mb) {
    int row = blockIdx.x;
    int tid = threadIdx.x;
    int wv  = tid >> 6;
#pragma unroll
    for (int w = 0; w < 8; w++) {
        int col = w * 256 + tid;
        int mval = mask[(size_t)row * SEQ + col];
        unsigned long long bits = __ballot(mval != 0);
        if ((tid & 63) == 0) mb[(size_t)row * 32 + w * 4 + wv] = bits;
    }
}

// ============ fused QKV GEMM: m97 structure, M=8192 N=3072 K=1024 =========
__global__ __launch_bounds__(256) void qkv_gemm(const unsigned short* __restrict__ xb,
                                                const unsigned short* __restrict__ wt,
                                                const float* __restrict__ bq,
                                                const float* __restrict__ bk,
                                                const float* __restrict__ bvv,
                                                unsigned short* __restrict__ qb,
                                                unsigned short* __restrict__ kb,
                                                unsigned short* __restrict__ vt) {
    __shared__ __align__(16) unsigned short lds_a[128 * 32];
    __shared__ __align__(16) unsigned short lds_b[128 * 32];
    int tid = threadIdx.x;
    int wave = tid >> 6, lane = tid & 63;
    int c = lane & 15, g = lane >> 4;
    int wave_m = (wave & 1) * 64, wave_n = (wave >> 1) * 64;
    int nblk = blockIdx.x * 128, mblk = blockIdx.y * 128;

    int oct0 = wave * 128 + lane, oct1 = oct0 + 64;
    int ra0 = oct0 >> 2, ga0 = ((oct0 & 3) ^ (ra0 & 3)) * 8;
    int ra1 = oct1 >> 2, ga1 = ((oct1 & 3) ^ (ra1 & 3)) * 8;
    const unsigned short* pa0 = xb + (size_t)(mblk + ra0) * D_MODEL + ga0;
    const unsigned short* pa1 = xb + (size_t)(mblk + ra1) * D_MODEL + ga1;
    const unsigned short* pb0 = wt + (size_t)(nblk + ra0) * D_MODEL + ga0;
    const unsigned short* pb1 = wt + (size_t)(nblk + ra1) * D_MODEL + ga1;
    unsigned short* la0 = lds_a + wave * 1024;
    unsigned short* la1 = la0 + 512;
    unsigned short* lb0 = lds_b + wave * 1024;
    unsigned short* lb1 = lb0 + 512;

    int aoff[4], boff[4];
#pragma unroll
    for (int mi = 0; mi < 4; mi++) {
        int row = wave_m + mi * 16 + c;
        aoff[mi] = (row * 4 + (g ^ (row & 3))) * 16;
    }
#pragma unroll
    for (int ni = 0; ni < 4; ni++) {
        int row = wave_n + ni * 16 + c;
        boff[ni] = (row * 4 + (g ^ (row & 3))) * 16;
    }

    f32x4 acc[4][4];
#pragma unroll
    for (int mi = 0; mi < 4; mi++)
#pragma unroll
        for (int ni = 0; ni < 4; ni++) acc[mi][ni] = f32x4{0.f, 0.f, 0.f, 0.f};

    for (int k0 = 0; k0 < D_MODEL; k0 += 32) {
        load_lds16(pa0 + k0, la0);
        load_lds16(pa1 + k0, la1);
        load_lds16(pb0 + k0, lb0);
        load_lds16(pb1 + k0, lb1);
        __syncthreads();
        bf16x8 af[4], bfr[4];
#pragma unroll
        for (int mi = 0; mi < 4; mi++)
            af[mi] = *reinterpret_cast<const bf16x8*>(reinterpret_cast<const char*>(lds_a) + aoff[mi]);
#pragma unroll
        for (int ni = 0; ni < 4; ni++)
            bfr[ni] = *reinterpret_cast<const bf16x8*>(reinterpret_cast<const char*>(lds_b) + boff[ni]);
#pragma unroll
        for (int mi = 0; mi < 4; mi++)
#pragma unroll
            for (int ni = 0; ni < 4; ni++)
                acc[mi][ni] = __builtin_amdgcn_mfma_f32_16x16x32_bf16(af[mi], bfr[ni], acc[mi][ni], 0, 0, 0);
        __syncthreads();
    }

    int nb = nblk + wave_n;
    int wsel = nb >> 10;
    int h = (nb >> 6) & 15;
    int dk0 = nb & 63;
    int mglob = mblk + wave_m;
    int b = mglob >> 11;
    int s0 = mglob & (SEQ - 1);
    size_t bh = (size_t)(b * N_HEADS + h);
    const float* bias = (wsel == 0) ? bq : (wsel == 1) ? bk : bvv;
    int nn = nb & (D_MODEL - 1);
    float bval[4];
#pragma unroll
    for (int ni = 0; ni < 4; ni++) bval[ni] = bias[nn + ni * 16 + c];
    float oscale = (wsel == 0) ? QSCALE : 1.0f;

    if (wsel < 2) {
        unsigned short* outp = wsel ? kb : qb;
#pragma unroll
        for (int mi = 0; mi < 4; mi++)
#pragma unroll
            for (int ni = 0; ni < 4; ni++) {
                int dk = dk0 + ni * 16 + c;
#pragma unroll
                for (int r = 0; r < 4; r++) {
                    int s = s0 + mi * 16 + g * 4 + r;
                    outp[(bh * SEQ + s) * 64 + dk] = f2bf((acc[mi][ni][r] + bval[ni]) * oscale);
                }
            }
    } else {
#pragma unroll
        for (int mi = 0; mi < 4; mi++)
#pragma unroll
            for (int ni = 0; ni < 4; ni++) {
                int dk = dk0 + ni * 16 + c;
                int s = s0 + mi * 16 + g * 4;
                ushort4v o;
#pragma unroll
                for (int r = 0; r < 4; r++) o[r] = f2bf(acc[mi][ni][r] + bval[ni]);
                *reinterpret_cast<ushort4v*>(vt + (bh * 64 + dk) * SEQ + s) = o;
            }
    }
}

// ==== flash attention v4: 32x32 MFMA, 32 q/wave, 2 waves/block ============
// S^T = K·Q^T and O^T = V^T·P^T keep query = lane&31 in all C/D layouts.
__global__ __launch_bounds__(128) void attn(const unsigned short* __restrict__ qb,
                                            const unsigned short* __restrict__ kb,
                                            const unsigned short* __restrict__ vt,
                                            const unsigned long long* __restrict__ mb,
                                            unsigned short* __restrict__ ctx) {
    __shared__ __align__(16) unsigned char smem[25088];
    unsigned short* lk = (unsigned short*)smem;            // [64 key][64 dk], octets xor row&7
    unsigned short* lv = (unsigned short*)(smem + 8192);   // [64 dk][64 key], octets xor row&7
    unsigned int*  lpw = (unsigned int*)(smem + 16384);    // per-wave [32 q][34 u32]

    int tid = threadIdx.x;
    int wave = tid >> 6, lane = tid & 63;
    int q31 = lane & 31, hi = lane >> 5;
    int bh = blockIdx.x >> 5;
    int q0 = (blockIdx.x & 31) * 64 + wave * 32;
    int b = bh >> 4, h = bh & 15;
    const unsigned short* qbase = qb + (size_t)bh * SEQ * 64;
    const unsigned short* kbase = kb + (size_t)bh * SEQ * 64;
    const unsigned short* vbase = vt + (size_t)bh * 64 * SEQ;
    const unsigned long long* mp = mb + ((size_t)b * SEQ + q0 + q31) * 32;

    // Q B-frags: chunk c covers dk = 16c + 8hi + (0..7)
    bf16x8 qf[4];
    {
        const unsigned short* qr = qbase + (size_t)(q0 + q31) * 64 + hi * 8;
#pragma unroll
        for (int c = 0; c < 4; c++)
            qf[c] = *reinterpret_cast<const bf16x8*>(qr + c * 16);
    }

    // staging: per glds instr, wave covers 8 rows x 128B; octet xored by row&7
    int srow = lane >> 3;
    int soct = (lane & 7) ^ srow;
    const unsigned short* ksrc[4];
    const unsigned short* vsrc[4];
    unsigned short* klb[4];
    unsigned short* vlb[4];
#pragma unroll
    for (int i = 0; i < 4; i++) {
        int rbase = 16 * i + 8 * wave;
        ksrc[i] = kbase + (size_t)(rbase + srow) * 64 + soct * 8;
        vsrc[i] = vbase + (size_t)(rbase + srow) * SEQ + soct * 8;
        klb[i] = lk + rbase * 64;
        vlb[i] = lv + rbase * 64;
    }

    // fragment byte offsets: subtile/tile s, chunk c
    int kofs[2][4];
#pragma unroll
    for (int s = 0; s < 2; s++)
#pragma unroll
        for (int c = 0; c < 4; c++)
            kofs[s][c] = (32 * s + q31) * 128 + (((hi + 2 * c) ^ (q31 & 7)) * 16);

    unsigned int* pw = lpw + wave * 1088 + q31 * 34 + 2 * hi;   // P write base
    const unsigned int* prd = lpw + wave * 1088 + q31 * 34 + 4 * hi; // P read base

    float lsum = 0.f;
    f32x16 po[2];
#pragma unroll
    for (int i = 0; i < 16; i++) { po[0][i] = 0.f; po[1][i] = 0.f; }

    for (int it = 0; it < SEQ / 64; it++) {
#pragma unroll
        for (int i = 0; i < 4; i++) {
            load_lds16(ksrc[i] + it * 4096, klb[i]);
            load_lds16(vsrc[i] + it * 64, vlb[i]);
        }
        unsigned long long w64 = mp[it];
        __syncthreads();

        const char* lkb = (const char*)lk;
        const char* lvb = (const char*)lv;

        // QK^T (S^T): A=K rows(keys), B=Q -> col=query
        f32x16 sq[2];
#pragma unroll
        for (int i = 0; i < 16; i++) { sq[0][i] = 0.f; sq[1][i] = 0.f; }
#pragma unroll
        for (int c = 0; c < 4; c++) {
            sq[0] = __builtin_amdgcn_mfma_f32_32x32x16_bf16(
                *reinterpret_cast<const bf16x8*>(lkb + kofs[0][c]), qf[c], sq[0], 0, 0, 0);
            sq[1] = __builtin_amdgcn_mfma_f32_32x32x16_bf16(
                *reinterpret_cast<const bf16x8*>(lkb + kofs[1][c]), qf[c], sq[1], 0, 0, 0);
        }

        // softmax numerators; key = 32s + 8j + 4hi + e  (reg r = 4j+e)
#pragma unroll
        for (int s = 0; s < 2; s++) {
            unsigned int wt = ~(unsigned int)(w64 >> (32 * s));   // bit=1 -> keep
#pragma unroll
            for (int j = 0; j < 4; j++) {
                unsigned int nj = wt >> (8 * j + 4 * hi);
                unsigned int t0, t1, t2, t3;
                {
                    float p = EXP2F(sq[s][4 * j + 0]);
                    unsigned int m = (unsigned int)((int)(nj << 31) >> 31);
                    t0 = __float_as_uint(p) & m; lsum += __uint_as_float(t0);
                }
                {
                    float p = EXP2F(sq[s][4 * j + 1]);
                    unsigned int m = (unsigned int)((int)(nj << 30) >> 31);
                    t1 = __float_as_uint(p) & m; lsum += __uint_as_float(t1);
                }
                {
                    float p = EXP2F(sq[s][4 * j + 2]);
                    unsigned int m = (unsigned int)((int)(nj << 29) >> 31);
                    t2 = __float_as_uint(p) & m; lsum += __uint_as_float(t2);
                }
                {
                    float p = EXP2F(sq[s][4 * j + 3]);
                    unsigned int m = (unsigned int)((int)(nj << 28) >> 31);
                    t3 = __float_as_uint(p) & m; lsum += __uint_as_float(t3);
                }
                uint2 u;
                u.x = (t0 >> 16) | (t1 & 0xFFFF0000u);
                u.y = (t2 >> 16) | (t3 & 0xFFFF0000u);
                *reinterpret_cast<uint2*>(pw + 16 * s + 4 * j) = u;
            }
        }

        // PV (O^T): A=V^T rows(dk), B=P^T -> col=query
#pragma unroll
        for (int c = 0; c < 4; c++) {
            union { bf16x8 v; uint4 u; } pb;
            uint2 b0 = *reinterpret_cast<const uint2*>(prd + 8 * c);
            uint2 b1 = *reinterpret_cast<const uint2*>(prd + 8 * c + 2);
            pb.u = make_uint4(b0.x, b0.y, b1.x, b1.y);
            po[0] = __builtin_amdgcn_mfma_f32_32x32x16_bf16(
                *reinterpret_cast<const bf16x8*>(lvb + kofs[0][c]), pb.v, po[0], 0, 0, 0);
            po[1] = __builtin_amdgcn_mfma_f32_32x32x16_bf16(
                *reinterpret_cast<const bf16x8*>(lvb + kofs[1][c]), pb.v, po[1], 0, 0, 0);
        }
        __syncthreads();
    }

    // finish row sums: lane(q,hi) holds half the keys; partner has the rest
    lsum += __shfl_xor(lsum, 32);
    float invr = 1.f / lsum;

    // epilogue: normalize O^T acc (dk = 32t + 8j + 4hi + e), bounce via LDS
    unsigned int* ob = (unsigned int*)smem + wave * 1152 + q31 * 36 + 2 * hi;
#pragma unroll
    for (int t = 0; t < 2; t++)
#pragma unroll
        for (int j = 0; j < 4; j++) {
            unsigned int w0 = (unsigned int)f2bf(po[t][4 * j + 0] * invr)
                            | ((unsigned int)f2bf(po[t][4 * j + 1] * invr) << 16);
            unsigned int w1 = (unsigned int)f2bf(po[t][4 * j + 2] * invr)
                            | ((unsigned int)f2bf(po[t][4 * j + 3] * invr) << 16);
            uint2 u; u.x = w0; u.y = w1;
            *reinterpret_cast<uint2*>(ob + 16 * t + 4 * j) = u;
        }

    // coalesced store: 4 x (8 rows x 128B)
    const unsigned int* obase = (const unsigned int*)smem + wave * 1152;
    size_t crow = (size_t)b * SEQ + q0;
#pragma unroll
    for (int i = 0; i < 4; i++) {
        int qq = i * 8 + (lane >> 3);
        int oo = lane & 7;
        uint4 v = *reinterpret_cast<const uint4*>(obase + qq * 36 + oo * 4);
        *reinterpret_cast<uint4*>(ctx + (crow + qq) * D_MODEL + h * 64 + oo * 8) = v;
    }
}

// ============ output projection: m97 structure, M=8192 N=1024 K=1024 ======
__global__ __launch_bounds__(256) void oproj(const unsigned short* __restrict__ ctx,
                                             const unsigned short* __restrict__ wt,
                                             const float* __restrict__ bo,
                                             float* __restrict__ out) {
    __shared__ __align__(16) unsigned short lds_a[128 * 32];
    __shared__ __align__(16) unsigned short lds_b[128 * 32];
    int tid = threadIdx.x;
    int wave = tid >> 6, lane = tid & 63;
    int c = lane & 15, g = lane >> 4;
    int wave_m = (wave & 1) * 64, wave_n = (wave >> 1) * 64;
    int nblk = blockIdx.x * 128, mblk = blockIdx.y * 128;
    const unsigned short* wo = wt + (size_t)3 * D_MODEL * D_MODEL;

    int oct0 = wave * 128 + lane, oct1 = oct0 + 64;
    int ra0 = oct0 >> 2, ga0 = ((oct0 & 3) ^ (ra0 & 3)) * 8;
    int ra1 = oct1 >> 2, ga1 = ((oct1 & 3) ^ (ra1 & 3)) * 8;
    const unsigned short* pa0 = ctx + (size_t)(mblk + ra0) * D_MODEL + ga0;
    const unsigned short* pa1 = ctx + (size_t)(mblk + ra1) * D_MODEL + ga1;
    const unsigned short* pb0 = wo + (size_t)(nblk + ra0) * D_MODEL + ga0;
    const unsigned short* pb1 = wo + (size_t)(nblk + ra1) * D_MODEL + ga1;
    unsigned short* la0 = lds_a + wave * 1024;
    unsigned short* la1 = la0 + 512;
    unsigned short* lb0 = lds_b + wave * 1024;
    unsigned short* lb1 = lb0 + 512;

    int aoff[4], boff[4];
#pragma unroll
    for (int mi = 0; mi < 4; mi++) {
        int row = wave_m + mi * 16 + c;
        aoff[mi] = (row * 4 + (g ^ (row & 3))) * 16;
    }
#pragma unroll
    for (int ni = 0; ni < 4; ni++) {
        int row = wave_n + ni * 16 + c;
        boff[ni] = (row * 4 + (g ^ (row & 3))) * 16;
    }

    f32x4 acc[4][4];
#pragma unroll
    for (int mi = 0; mi < 4; mi++)
#pragma unroll
        for (int ni = 0; ni < 4; ni++) acc[mi][ni] = f32x4{0.f, 0.f, 0.f, 0.f};

    for (int k0 = 0; k0 < D_MODEL; k0 += 32) {
        load_lds16(pa0 + k0, la0);
        load_lds16(pa1 + k0, la1);
        load_lds16(pb0 + k0, lb0);
        load_lds16(pb1 + k0, lb1);
        __syncthreads();
        bf16x8 af[4], bfr[4];
#pragma unroll
        for (int mi = 0; mi < 4; mi++)
            af[mi] = *reinterpret_cast<const bf16x8*>(reinterpret_cast<const char*>(lds_a) + aoff[mi]);
#pragma unroll
        for (int ni = 0; ni < 4; ni++)
            bfr[ni] = *reinterpret_cast<const bf16x8*>(reinterpret_cast<const char*>(lds_b) + boff[ni]);
#pragma unroll
        for (int mi = 0; mi < 4; mi++)
#pragma unroll
            for (int ni = 0; ni < 4; ni++)
                acc[mi][ni] = __builtin_amdgcn_mfma_f32_16x16x32_bf16(af[mi], bfr[ni], acc[mi][ni], 0, 0, 0);
        __syncthreads();
    }

    float bval[4];
#pragma unroll
    for (int ni = 0; ni < 4; ni++) bval[ni] = bo[nblk + wave_n + ni * 16 + c];
#pragma unroll
    for (int mi = 0; mi < 4; mi++)
#pragma unroll
        for (int ni = 0; ni < 4; ni++) {
            int n = nblk + wave_n + ni * 16 + c;
#pragma unroll
            for (int r = 0; r < 4; r++) {
                int m = mblk + wave_m + mi * 16 + g * 4 + r;
                out[(size_t)m * D_MODEL + n] = acc[mi][ni][r] + bval[ni];
            }
        }
}

extern "C" void kernel_launch(void* const* d_in, const int* in_sizes, int n_in,
                              void* d_out, int out_size, void* d_ws, size_t ws_size,
                              hipStream_t stream) {
    const float* x    = (const float*)d_in[0];
    const int*   mask = (const int*)d_in[1];
    const float* Wq = (const float*)d_in[2];
    const float* bq = (const float*)d_in[3];
    const float* Wk = (const float*)d_in[4];
    const float* bk = (const float*)d_in[5];
    const float* Wv = (const float*)d_in[6];
    const float* bv = (const float*)d_in[7];
    const float* Wo = (const float*)d_in[8];
    const float* bo = (const float*)d_in[9];
    float* out = (float*)d_out;

    char* ws = (char*)d_ws;
    const size_t MB = 1024 * 1024;
    unsigned short* wt  = (unsigned short*)(ws + 0 * MB);
    unsigned short* xb  = (unsigned short*)(ws + 8 * MB);
    unsigned short* qb  = (unsigned short*)(ws + 24 * MB);
    unsigned short* kb  = (unsigned short*)(ws + 40 * MB);
    unsigned short* vt  = (unsigned short*)(ws + 56 * MB);
    unsigned short* ctx = (unsigned short*)(ws + 72 * MB);
    unsigned long long* mb = (unsigned long long*)(ws + 88 * MB);

    wprep<<<dim3(16, 16, 4), 256, 0, stream>>>(Wq, Wk, Wv, Wo, wt);
    xprep<<<dim3(MROWS * D_MODEL / 4 / 256), 256, 0, stream>>>((const float4*)x, xb);
    mprep<<<dim3(MROWS), 256, 0, stream>>>(mask, mb);
    qkv_gemm<<<dim3(24, 64), 256, 0, stream>>>(xb, wt, bq, bk, bv, qb, kb, vt);
    attn<<<dim3(2048), 128, 0, stream>>>(qb, kb, vt, mb, ctx);
    oproj<<<dim3(8, 64), 256, 0, stream>>>(ctx, wt, bo, out);
}

// Round 6
// 376.783 us; speedup vs baseline: 1.0958x; 1.0921x over previous
//
#include <hip/hip_runtime.h>

#define D_MODEL 1024
#define N_HEADS 16
#define D_K     64
#define BATCH   4
#define SEQ     2048
#define MROWS   (BATCH * SEQ)          // 8192
// Q pre-scale: (1/sqrt(64)) * log2(e) so attn uses raw exp2
#define QSCALE  0.18033688011112042f

typedef __bf16 bf16x8 __attribute__((ext_vector_type(8)));
typedef float  f32x4  __attribute__((ext_vector_type(4)));
typedef float  f32x16 __attribute__((ext_vector_type(16)));
typedef unsigned short ushort8 __attribute__((ext_vector_type(8)));
typedef unsigned short ushort4v __attribute__((ext_vector_type(4)));

#if __has_builtin(__builtin_amdgcn_exp2f)
#define EXP2F(x) __builtin_amdgcn_exp2f(x)
#else
#define EXP2F(x) exp2f(x)
#endif

__device__ inline unsigned short f2bf(float f) {
    union { float f; unsigned int u; } v; v.f = f;
    unsigned int u = v.u;
    unsigned int r = (u + 0x7fffu + ((u >> 16) & 1u)) >> 16;
    return (unsigned short)r;
}

__device__ inline void load_lds16(const void* g, void* l) {
    __builtin_amdgcn_global_load_lds(
        (const __attribute__((address_space(1))) unsigned int*)g,
        (__attribute__((address_space(3))) unsigned int*)l, 16, 0, 0);
}

// ---------------- prep: weights fp32 [K][N] -> bf16 [N][K] ----------------
__global__ __launch_bounds__(256) void wprep(const float* __restrict__ Wq,
                                             const float* __restrict__ Wk,
                                             const float* __restrict__ Wv,
                                             const float* __restrict__ Wo,
                                             unsigned short* __restrict__ wt) {
    __shared__ __align__(16) unsigned short t[64][65];
    int w  = blockIdx.z;
    const float* W = (w == 0) ? Wq : (w == 1) ? Wk : (w == 2) ? Wv : Wo;
    int k0 = blockIdx.x * 64, n0 = blockIdx.y * 64;
    int tid = threadIdx.x;
    int nl = tid & 63, kq = tid >> 6;
#pragma unroll
    for (int i = 0; i < 16; i++) {
        int kl = kq * 16 + i;
        t[kl][nl] = f2bf(W[(size_t)(k0 + kl) * D_MODEL + n0 + nl]);
    }
    __syncthreads();
    unsigned short* out = wt + (size_t)w * D_MODEL * D_MODEL;
#pragma unroll
    for (int p = 0; p < 2; p++) {
        int nrow = p * 32 + (tid >> 3);
        int c8   = (tid & 7) * 8;
        ushort8 o;
#pragma unroll
        for (int j = 0; j < 8; j++) o[j] = t[c8 + j][nrow];
        *reinterpret_cast<ushort8*>(out + (size_t)(n0 + nrow) * D_MODEL + k0 + c8) = o;
    }
}

// ---------------- prep: x fp32 -> bf16 ----------------
__global__ __launch_bounds__(256) void xprep(const float4* __restrict__ x,
                                             unsigned short* __restrict__ xb) {
    int i = blockIdx.x * 256 + threadIdx.x;
    float4 v = x[i];
    ushort4v o;
    o[0] = f2bf(v.x); o[1] = f2bf(v.y); o[2] = f2bf(v.z); o[3] = f2bf(v.w);
    *reinterpret_cast<ushort4v*>(xb + (size_t)i * 4) = o;
}

// ---------------- prep: mask int32 -> bitmask (bit=1 means masked) --------
__global__ __launch_bounds__(256) void mprep(const int* __restrict__ mask,
                                             unsigned long long* __restrict__ mb) {
    int row = blockIdx.x;
    int tid = threadIdx.x;
    int wv  = tid >> 6;
#pragma unroll
    for (int w = 0; w < 8; w++) {
        int col = w * 256 + tid;
        int mval = mask[(size_t)row * SEQ + col];
        unsigned long long bits = __ballot(mval != 0);
        if ((tid & 63) == 0) mb[(size_t)row * 32 + w * 4 + wv] = bits;
    }
}

// ============ fused QKV GEMM: m97 structure, M=8192 N=3072 K=1024 =========
__global__ __launch_bounds__(256) void qkv_gemm(const unsigned short* __restrict__ xb,
                                                const unsigned short* __restrict__ wt,
                                                const float* __restrict__ bq,
                                                const float* __restrict__ bk,
                                                const float* __restrict__ bvv,
                                                unsigned short* __restrict__ qb,
                                                unsigned short* __restrict__ kb,
                                                unsigned short* __restrict__ vt) {
    __shared__ __align__(16) unsigned short lds_a[128 * 32];
    __shared__ __align__(16) unsigned short lds_b[128 * 32];
    int tid = threadIdx.x;
    int wave = tid >> 6, lane = tid & 63;
    int c = lane & 15, g = lane >> 4;
    int wave_m = (wave & 1) * 64, wave_n = (wave >> 1) * 64;
    int nblk = blockIdx.x * 128, mblk = blockIdx.y * 128;

    int oct0 = wave * 128 + lane, oct1 = oct0 + 64;
    int ra0 = oct0 >> 2, ga0 = ((oct0 & 3) ^ (ra0 & 3)) * 8;
    int ra1 = oct1 >> 2, ga1 = ((oct1 & 3) ^ (ra1 & 3)) * 8;
    const unsigned short* pa0 = xb + (size_t)(mblk + ra0) * D_MODEL + ga0;
    const unsigned short* pa1 = xb + (size_t)(mblk + ra1) * D_MODEL + ga1;
    const unsigned short* pb0 = wt + (size_t)(nblk + ra0) * D_MODEL + ga0;
    const unsigned short* pb1 = wt + (size_t)(nblk + ra1) * D_MODEL + ga1;
    unsigned short* la0 = lds_a + wave * 1024;
    unsigned short* la1 = la0 + 512;
    unsigned short* lb0 = lds_b + wave * 1024;
    unsigned short* lb1 = lb0 + 512;

    int aoff[4], boff[4];
#pragma unroll
    for (int mi = 0; mi < 4; mi++) {
        int row = wave_m + mi * 16 + c;
        aoff[mi] = (row * 4 + (g ^ (row & 3))) * 16;
    }
#pragma unroll
    for (int ni = 0; ni < 4; ni++) {
        int row = wave_n + ni * 16 + c;
        boff[ni] = (row * 4 + (g ^ (row & 3))) * 16;
    }

    f32x4 acc[4][4];
#pragma unroll
    for (int mi = 0; mi < 4; mi++)
#pragma unroll
        for (int ni = 0; ni < 4; ni++) acc[mi][ni] = f32x4{0.f, 0.f, 0.f, 0.f};

    for (int k0 = 0; k0 < D_MODEL; k0 += 32) {
        load_lds16(pa0 + k0, la0);
        load_lds16(pa1 + k0, la1);
        load_lds16(pb0 + k0, lb0);
        load_lds16(pb1 + k0, lb1);
        __syncthreads();
        bf16x8 af[4], bfr[4];
#pragma unroll
        for (int mi = 0; mi < 4; mi++)
            af[mi] = *reinterpret_cast<const bf16x8*>(reinterpret_cast<const char*>(lds_a) + aoff[mi]);
#pragma unroll
        for (int ni = 0; ni < 4; ni++)
            bfr[ni] = *reinterpret_cast<const bf16x8*>(reinterpret_cast<const char*>(lds_b) + boff[ni]);
#pragma unroll
        for (int mi = 0; mi < 4; mi++)
#pragma unroll
            for (int ni = 0; ni < 4; ni++)
                acc[mi][ni] = __builtin_amdgcn_mfma_f32_16x16x32_bf16(af[mi], bfr[ni], acc[mi][ni], 0, 0, 0);
        __syncthreads();
    }

    int nb = nblk + wave_n;
    int wsel = nb >> 10;
    int h = (nb >> 6) & 15;
    int dk0 = nb & 63;
    int mglob = mblk + wave_m;
    int b = mglob >> 11;
    int s0 = mglob & (SEQ - 1);
    size_t bh = (size_t)(b * N_HEADS + h);
    const float* bias = (wsel == 0) ? bq : (wsel == 1) ? bk : bvv;
    int nn = nb & (D_MODEL - 1);
    float bval[4];
#pragma unroll
    for (int ni = 0; ni < 4; ni++) bval[ni] = bias[nn + ni * 16 + c];
    float oscale = (wsel == 0) ? QSCALE : 1.0f;

    if (wsel < 2) {
        unsigned short* outp = wsel ? kb : qb;
#pragma unroll
        for (int mi = 0; mi < 4; mi++)
#pragma unroll
            for (int ni = 0; ni < 4; ni++) {
                int dk = dk0 + ni * 16 + c;
#pragma unroll
                for (int r = 0; r < 4; r++) {
                    int s = s0 + mi * 16 + g * 4 + r;
                    outp[(bh * SEQ + s) * 64 + dk] = f2bf((acc[mi][ni][r] + bval[ni]) * oscale);
                }
            }
    } else {
#pragma unroll
        for (int mi = 0; mi < 4; mi++)
#pragma unroll
            for (int ni = 0; ni < 4; ni++) {
                int dk = dk0 + ni * 16 + c;
                int s = s0 + mi * 16 + g * 4;
                ushort4v o;
#pragma unroll
                for (int r = 0; r < 4; r++) o[r] = f2bf(acc[mi][ni][r] + bval[ni]);
                *reinterpret_cast<ushort4v*>(vt + (bh * 64 + dk) * SEQ + s) = o;
            }
    }
}

// ==== flash attention v6: 64 q/wave (2 tiles), 2-barrier loop, K/V reuse ===
__global__ __launch_bounds__(128, 2) void attn(const unsigned short* __restrict__ qb,
                                               const unsigned short* __restrict__ kb,
                                               const unsigned short* __restrict__ vt,
                                               const unsigned long long* __restrict__ mb,
                                               unsigned short* __restrict__ ctx) {
    __shared__ __align__(16) unsigned char smem[36864];
    unsigned short* lk = (unsigned short*)smem;            // [64 key][64 dk], octet^row&7
    unsigned short* lv = (unsigned short*)(smem + 8192);   // [64 dk][64 key], octet^row&7
    unsigned int*  lpA = (unsigned int*)(smem + 16384);    // P: wave*2560 + (t*2+s)*640 + q*20

    int tid = threadIdx.x;
    int wave = tid >> 6, lane = tid & 63;
    int q31 = lane & 31, hi = lane >> 5;
    int bh = blockIdx.x >> 4;
    int q0 = (blockIdx.x & 15) * 128 + wave * 64;
    int b = bh >> 4, h = bh & 15;
    const unsigned short* qbase = qb + (size_t)bh * SEQ * 64;
    const unsigned short* kbase = kb + (size_t)bh * SEQ * 64;
    const unsigned short* vbase = vt + (size_t)bh * 64 * SEQ;
    const unsigned long long* mp0 = mb + ((size_t)b * SEQ + q0 + q31) * 32;
    const unsigned long long* mp1 = mp0 + 1024;   // +32 rows * 32 words

    // Q B-frags for both tiles: chunk c covers dk = 16c + 8hi + (0..7)
    bf16x8 qf[2][4];
#pragma unroll
    for (int t = 0; t < 2; t++) {
        const unsigned short* qr = qbase + (size_t)(q0 + 32 * t + q31) * 64 + hi * 8;
#pragma unroll
        for (int c = 0; c < 4; c++)
            qf[t][c] = *reinterpret_cast<const bf16x8*>(qr + c * 16);
    }

    // staging: 8 rows x 128B per glds; octet xor (row&7)
    int srow = lane >> 3;
    int soct = (lane & 7) ^ srow;
    const unsigned short* ksrc[4];
    const unsigned short* vsrc[4];
    unsigned short* klb[4];
    unsigned short* vlb[4];
#pragma unroll
    for (int i = 0; i < 4; i++) {
        int rbase = 16 * i + 8 * wave;
        ksrc[i] = kbase + (size_t)(rbase + srow) * 64 + soct * 8;
        vsrc[i] = vbase + (size_t)(rbase + srow) * SEQ + soct * 8;
        klb[i] = lk + rbase * 64;
        vlb[i] = lv + rbase * 64;
    }

    // K/V fragment byte offsets: subtile s (rows 32s..), chunk c
    int kofs[2][4];
#pragma unroll
    for (int s = 0; s < 2; s++)
#pragma unroll
        for (int c = 0; c < 4; c++)
            kofs[s][c] = (32 * s + q31) * 128 + (((hi + 2 * c) ^ (q31 & 7)) * 16);

    unsigned int* lp = lpA + wave * 2560 + q31 * 20;   // + (t*2+s)*640

    float lsum[2] = {0.f, 0.f};
    f32x16 po[2][2];
#pragma unroll
    for (int i = 0; i < 16; i++) {
        po[0][0][i] = 0.f; po[0][1][i] = 0.f;
        po[1][0][i] = 0.f; po[1][1][i] = 0.f;
    }

    for (int it = 0; it < SEQ / 64; it++) {
#pragma unroll
        for (int i = 0; i < 4; i++) {
            load_lds16(ksrc[i] + it * 4096, klb[i]);
            load_lds16(vsrc[i] + it * 64, vlb[i]);
        }
        unsigned long long w64[2];
        w64[0] = mp0[it];
        w64[1] = mp1[it];
        __syncthreads();

        const char* lkb = (const char*)lk;
        const char* lvb = (const char*)lv;

#pragma unroll
        for (int s = 0; s < 2; s++) {
            // QK^T (S^T): A=K rows(keys 32s..32s+31), B=Q[t] -> col=query
            f32x16 sq[2];
#pragma unroll
            for (int i = 0; i < 16; i++) { sq[0][i] = 0.f; sq[1][i] = 0.f; }
#pragma unroll
            for (int c = 0; c < 4; c++) {
                bf16x8 kf = *reinterpret_cast<const bf16x8*>(lkb + kofs[s][c]);
                sq[0] = __builtin_amdgcn_mfma_f32_32x32x16_bf16(kf, qf[0][c], sq[0], 0, 0, 0);
                sq[1] = __builtin_amdgcn_mfma_f32_32x32x16_bf16(kf, qf[1][c], sq[1], 0, 0, 0);
            }
            // softmax numerators; key(within subtile) = 8j + 4hi + e
#pragma unroll
            for (int t = 0; t < 2; t++) {
                unsigned int wt_ = ~(unsigned int)(w64[t] >> (32 * s));   // bit=1 -> keep
                unsigned int* pw = lp + (t * 2 + s) * 640;
#pragma unroll
                for (int j = 0; j < 4; j++) {
                    unsigned int nj = wt_ >> (8 * j + 4 * hi);
                    unsigned int t0, t1, t2, t3;
                    {
                        float p = EXP2F(sq[t][4 * j + 0]);
                        unsigned int m = (unsigned int)((int)(nj << 31) >> 31);
                        t0 = __float_as_uint(p) & m; lsum[t] += __uint_as_float(t0);
                    }
                    {
                        float p = EXP2F(sq[t][4 * j + 1]);
                        unsigned int m = (unsigned int)((int)(nj << 30) >> 31);
                        t1 = __float_as_uint(p) & m; lsum[t] += __uint_as_float(t1);
                    }
                    {
                        float p = EXP2F(sq[t][4 * j + 2]);
                        unsigned int m = (unsigned int)((int)(nj << 29) >> 31);
                        t2 = __float_as_uint(p) & m; lsum[t] += __uint_as_float(t2);
                    }
                    {
                        float p = EXP2F(sq[t][4 * j + 3]);
                        unsigned int m = (unsigned int)((int)(nj << 28) >> 31);
                        t3 = __float_as_uint(p) & m; lsum[t] += __uint_as_float(t3);
                    }
                    uint2 u;
                    u.x = (t0 >> 16) | (t1 & 0xFFFF0000u);
                    u.y = (t2 >> 16) | (t3 & 0xFFFF0000u);
                    *reinterpret_cast<uint2*>(pw + 4 * j + 2 * hi) = u;
                }
            }
            // PV (O^T): chunks c = 2s, 2s+1; A=V^T rows(dk), B=P^T -> col=query
#pragma unroll
            for (int cp = 0; cp < 2; cp++) {
                int c = 2 * s + cp;
                union { bf16x8 v; uint4 u; } pb0, pb1;
                pb0.u = *reinterpret_cast<const uint4*>(lp + (0 * 2 + s) * 640 + 8 * cp + 4 * hi);
                pb1.u = *reinterpret_cast<const uint4*>(lp + (1 * 2 + s) * 640 + 8 * cp + 4 * hi);
#pragma unroll
                for (int so = 0; so < 2; so++) {
                    bf16x8 vf = *reinterpret_cast<const bf16x8*>(lvb + kofs[so][c]);
                    po[0][so] = __builtin_amdgcn_mfma_f32_32x32x16_bf16(vf, pb0.v, po[0][so], 0, 0, 0);
                    po[1][so] = __builtin_amdgcn_mfma_f32_32x32x16_bf16(vf, pb1.v, po[1][so], 0, 0, 0);
                }
            }
        }
        __syncthreads();
    }

    // finish row sums: partner (lane^32) holds the complementary key halves
    float inv[2];
#pragma unroll
    for (int t = 0; t < 2; t++) {
        lsum[t] += __shfl_xor(lsum[t], 32);
        inv[t] = 1.f / lsum[t];
    }

    // epilogue: normalize O^T (dk = 32so + 8j + 4hi + e), bounce via LDS
    // (safe: loop ended with __syncthreads)
    unsigned int* ob = (unsigned int*)(smem + wave * 8192);
    int csw = 4 * (q31 & 7);
#pragma unroll
    for (int t = 0; t < 2; t++) {
        unsigned int* obr = ob + (32 * t + q31) * 32;
#pragma unroll
        for (int so = 0; so < 2; so++)
#pragma unroll
            for (int j = 0; j < 4; j++) {
                unsigned int w0 = (unsigned int)f2bf(po[t][so][4 * j + 0] * inv[t])
                                | ((unsigned int)f2bf(po[t][so][4 * j + 1] * inv[t]) << 16);
                unsigned int w1 = (unsigned int)f2bf(po[t][so][4 * j + 2] * inv[t])
                                | ((unsigned int)f2bf(po[t][so][4 * j + 3] * inv[t]) << 16);
                int d = (16 * so + 4 * j + 2 * hi) ^ csw;
                uint2 u; u.x = w0; u.y = w1;
                *reinterpret_cast<uint2*>(obr + d) = u;
            }
    }
    __builtin_amdgcn_s_waitcnt(0);   // drain own ds_writes (wave-private region)
    size_t crow = (size_t)b * SEQ + q0;
    int o = lane & 7, rl = lane >> 3;
#pragma unroll
    for (int i = 0; i < 8; i++) {
        int r = 8 * i + rl;
        uint4 v = *reinterpret_cast<const uint4*>(ob + r * 32 + 4 * (o ^ (r & 7)));
        *reinterpret_cast<uint4*>(ctx + (crow + r) * D_MODEL + h * 64 + o * 8) = v;
    }
}

// ============ output projection: m97 structure, M=8192 N=1024 K=1024 ======
__global__ __launch_bounds__(256) void oproj(const unsigned short* __restrict__ ctx,
                                             const unsigned short* __restrict__ wt,
                                             const float* __restrict__ bo,
                                             float* __restrict__ out) {
    __shared__ __align__(16) unsigned short lds_a[128 * 32];
    __shared__ __align__(16) unsigned short lds_b[128 * 32];
    int tid = threadIdx.x;
    int wave = tid >> 6, lane = tid & 63;
    int c = lane & 15, g = lane >> 4;
    int wave_m = (wave & 1) * 64, wave_n = (wave >> 1) * 64;
    int nblk = blockIdx.x * 128, mblk = blockIdx.y * 128;
    const unsigned short* wo = wt + (size_t)3 * D_MODEL * D_MODEL;

    int oct0 = wave * 128 + lane, oct1 = oct0 + 64;
    int ra0 = oct0 >> 2, ga0 = ((oct0 & 3) ^ (ra0 & 3)) * 8;
    int ra1 = oct1 >> 2, ga1 = ((oct1 & 3) ^ (ra1 & 3)) * 8;
    const unsigned short* pa0 = ctx + (size_t)(mblk + ra0) * D_MODEL + ga0;
    const unsigned short* pa1 = ctx + (size_t)(mblk + ra1) * D_MODEL + ga1;
    const unsigned short* pb0 = wo + (size_t)(nblk + ra0) * D_MODEL + ga0;
    const unsigned short* pb1 = wo + (size_t)(nblk + ra1) * D_MODEL + ga1;
    unsigned short* la0 = lds_a + wave * 1024;
    unsigned short* la1 = la0 + 512;
    unsigned short* lb0 = lds_b + wave * 1024;
    unsigned short* lb1 = lb0 + 512;

    int aoff[4], boff[4];
#pragma unroll
    for (int mi = 0; mi < 4; mi++) {
        int row = wave_m + mi * 16 + c;
        aoff[mi] = (row * 4 + (g ^ (row & 3))) * 16;
    }
#pragma unroll
    for (int ni = 0; ni < 4; ni++) {
        int row = wave_n + ni * 16 + c;
        boff[ni] = (row * 4 + (g ^ (row & 3))) * 16;
    }

    f32x4 acc[4][4];
#pragma unroll
    for (int mi = 0; mi < 4; mi++)
#pragma unroll
        for (int ni = 0; ni < 4; ni++) acc[mi][ni] = f32x4{0.f, 0.f, 0.f, 0.f};

    for (int k0 = 0; k0 < D_MODEL; k0 += 32) {
        load_lds16(pa0 + k0, la0);
        load_lds16(pa1 + k0, la1);
        load_lds16(pb0 + k0, lb0);
        load_lds16(pb1 + k0, lb1);
        __syncthreads();
        bf16x8 af[4], bfr[4];
#pragma unroll
        for (int mi = 0; mi < 4; mi++)
            af[mi] = *reinterpret_cast<const bf16x8*>(reinterpret_cast<const char*>(lds_a) + aoff[mi]);
#pragma unroll
        for (int ni = 0; ni < 4; ni++)
            bfr[ni] = *reinterpret_cast<const bf16x8*>(reinterpret_cast<const char*>(lds_b) + boff[ni]);
#pragma unroll
        for (int mi = 0; mi < 4; mi++)
#pragma unroll
            for (int ni = 0; ni < 4; ni++)
                acc[mi][ni] = __builtin_amdgcn_mfma_f32_16x16x32_bf16(af[mi], bfr[ni], acc[mi][ni], 0, 0, 0);
        __syncthreads();
    }

    float bval[4];
#pragma unroll
    for (int ni = 0; ni < 4; ni++) bval[ni] = bo[nblk + wave_n + ni * 16 + c];
#pragma unroll
    for (int mi = 0; mi < 4; mi++)
#pragma unroll
        for (int ni = 0; ni < 4; ni++) {
            int n = nblk + wave_n + ni * 16 + c;
#pragma unroll
            for (int r = 0; r < 4; r++) {
                int m = mblk + wave_m + mi * 16 + g * 4 + r;
                out[(size_t)m * D_MODEL + n] = acc[mi][ni][r] + bval[ni];
            }
        }
}

extern "C" void kernel_launch(void* const* d_in, const int* in_sizes, int n_in,
                              void* d_out, int out_size, void* d_ws, size_t ws_size,
                              hipStream_t stream) {
    const float* x    = (const float*)d_in[0];
    const int*   mask = (const int*)d_in[1];
    const float* Wq = (const float*)d_in[2];
    const float* bq = (const float*)d_in[3];
    const float* Wk = (const float*)d_in[4];
    const float* bk = (const float*)d_in[5];
    const float* Wv = (const float*)d_in[6];
    const float* bv = (const float*)d_in[7];
    const float* Wo = (const float*)d_in[8];
    const float* bo = (const float*)d_in[9];
    float* out = (float*)d_out;

    char* ws = (char*)d_ws;
    const size_t MB = 1024 * 1024;
    unsigned short* wt  = (unsigned short*)(ws + 0 * MB);
    unsigned short* xb  = (unsigned short*)(ws + 8 * MB);
    unsigned short* qb  = (unsigned short*)(ws + 24 * MB);
    unsigned short* kb  = (unsigned short*)(ws + 40 * MB);
    unsigned short* vt  = (unsigned short*)(ws + 56 * MB);
    unsigned short* ctx = (unsigned short*)(ws + 72 * MB);
    unsigned long long* mb = (unsigned long long*)(ws + 88 * MB);

    wprep<<<dim3(16, 16, 4), 256, 0, stream>>>(Wq, Wk, Wv, Wo, wt);
    xprep<<<dim3(MROWS * D_MODEL / 4 / 256), 256, 0, stream>>>((const float4*)x, xb);
    mprep<<<dim3(MROWS), 256, 0, stream>>>(mask, mb);
    qkv_gemm<<<dim3(24, 64), 256, 0, stream>>>(xb, wt, bq, bk, bv, qb, kb, vt);
    attn<<<dim3(1024), 128, 0, stream>>>(qb, kb, vt, mb, ctx);
    oproj<<<dim3(8, 64), 256, 0, stream>>>(ctx, wt, bo, out);
}